// Round 5
// baseline (140.628 us; speedup 1.0000x reference)
//
#include <hip/hip_runtime.h>
#include <math.h>

#define PI_F 3.14159265358979323846f
#define FLAG_MAGIC 0x5EEDCAFEu

__device__ __forceinline__ float rcpf(float x) { return __builtin_amdgcn_rcpf(x); }
__device__ __forceinline__ void fswap(float2& p, float2& q) { float2 t = p; p = q; q = t; }

// ---------------------------------------------------------------------------
// QCNN per-wave register statevector (identical math to round 4).
// Amp mapping: qubit0 -> reg bit1, qubit1 -> reg bit0, qubit q>=2 -> lane bit (q-2).
// ---------------------------------------------------------------------------

template<int Q>
__device__ __forceinline__ float exq(float v) {
    if constexpr (Q == 2)
        return __int_as_float(__builtin_amdgcn_update_dpp(0, __float_as_int(v), 0xB1, 0xF, 0xF, true));
    else if constexpr (Q == 3)
        return __int_as_float(__builtin_amdgcn_update_dpp(0, __float_as_int(v), 0x4E, 0xF, 0xF, true));
    else if constexpr (Q == 4)
        return __int_as_float(__builtin_amdgcn_ds_swizzle(__float_as_int(v), 0x101F));
    else if constexpr (Q == 5)
        return __int_as_float(__builtin_amdgcn_ds_swizzle(__float_as_int(v), 0x201F));
    else if constexpr (Q == 6)
        return __int_as_float(__builtin_amdgcn_ds_swizzle(__float_as_int(v), 0x401F));
    else
        return __shfl_xor(v, 32, 64);
}

template<int Q>
__device__ __forceinline__ void rzg(float2 a[4], float th, int lane) {
    float c = __cosf(0.5f * th), s = __sinf(0.5f * th);
    if constexpr (Q >= 2) {
        float se = ((lane >> (Q - 2)) & 1) ? s : -s;
        #pragma unroll
        for (int r = 0; r < 4; ++r) {
            float nx = c * a[r].x - se * a[r].y;
            float ny = c * a[r].y + se * a[r].x;
            a[r] = make_float2(nx, ny);
        }
    } else {
        #pragma unroll
        for (int r = 0; r < 4; ++r) {
            int bit = (Q == 0) ? (r >> 1) : (r & 1);
            float se = bit ? s : -s;
            float nx = c * a[r].x - se * a[r].y;
            float ny = c * a[r].y + se * a[r].x;
            a[r] = make_float2(nx, ny);
        }
    }
}

template<int Q>
__device__ __forceinline__ void ryg(float2 a[4], float th, int lane) {
    float c = __cosf(0.5f * th), s = __sinf(0.5f * th);
    if constexpr (Q >= 2) {
        float se = ((lane >> (Q - 2)) & 1) ? s : -s;
        #pragma unroll
        for (int r = 0; r < 4; ++r) {
            float ox = exq<Q>(a[r].x), oy = exq<Q>(a[r].y);
            a[r] = make_float2(c * a[r].x + se * ox, c * a[r].y + se * oy);
        }
    } else if constexpr (Q == 0) {
        #pragma unroll
        for (int r = 0; r < 2; ++r) {
            float2 lo = a[r], hi = a[r + 2];
            a[r]     = make_float2(c * lo.x - s * hi.x, c * lo.y - s * hi.y);
            a[r + 2] = make_float2(s * lo.x + c * hi.x, s * lo.y + c * hi.y);
        }
    } else {
        #pragma unroll
        for (int r = 0; r < 4; r += 2) {
            float2 lo = a[r], hi = a[r + 1];
            a[r]     = make_float2(c * lo.x - s * hi.x, c * lo.y - s * hi.y);
            a[r + 1] = make_float2(s * lo.x + c * hi.x, s * lo.y + c * hi.y);
        }
    }
}

template<int C, int T>
__device__ __forceinline__ void cxg(float2 a[4], int lane) {
    if constexpr (C >= 2) {
        bool cb = (lane >> (C - 2)) & 1;
        #pragma unroll
        for (int r = 0; r < 4; ++r) {
            float ox = exq<T>(a[r].x), oy = exq<T>(a[r].y);
            a[r].x = cb ? ox : a[r].x;
            a[r].y = cb ? oy : a[r].y;
        }
    } else if constexpr (C == 0 && T == 1) {
        fswap(a[2], a[3]);
    } else {
        fswap(a[1], a[3]);
    }
}

template<int Q>
__device__ __forceinline__ void featg(float2 a[4], float xq, int lane) {
    float phi = 2.0f * xq;
    float e1x = __cosf(phi), e1y = __sinf(phi);
    float e2x = e1x * e1x - e1y * e1y;
    float e2y = 2.0f * e1x * e1y;
    float2 u00 = make_float2(0.5f * (1.0f + e1x),  0.5f * e1y);
    float2 u01 = make_float2(0.5f * (1.0f - e1x), -0.5f * e1y);
    float2 u10 = make_float2(0.5f * (e1x - e2x), 0.5f * (e1y - e2y));
    float2 u11 = make_float2(0.5f * (e1x + e2x), 0.5f * (e1y + e2y));
    if constexpr (Q >= 2) {
        bool bset = (lane >> (Q - 2)) & 1;
        float csx = bset ? u11.x : u00.x, csy = bset ? u11.y : u00.y;
        float cox = bset ? u10.x : u01.x, coy = bset ? u10.y : u01.y;
        #pragma unroll
        for (int r = 0; r < 4; ++r) {
            float ox = exq<Q>(a[r].x), oy = exq<Q>(a[r].y);
            float nx = csx * a[r].x - csy * a[r].y + cox * ox - coy * oy;
            float ny = csx * a[r].y + csy * a[r].x + cox * oy + coy * ox;
            a[r] = make_float2(nx, ny);
        }
    } else {
        float2 l, h;
        #define APPL(LO, HI)                                                        \
            l = a[LO]; h = a[HI];                                                   \
            a[LO] = make_float2(u00.x*l.x - u00.y*l.y + u01.x*h.x - u01.y*h.y,      \
                                u00.x*l.y + u00.y*l.x + u01.x*h.y + u01.y*h.x);     \
            a[HI] = make_float2(u10.x*l.x - u10.y*l.y + u11.x*h.x - u11.y*h.y,      \
                                u10.x*l.y + u10.y*l.x + u11.x*h.y + u11.y*h.x);
        if constexpr (Q == 0) { APPL(0, 2) APPL(1, 3) }
        else                  { APPL(0, 1) APPL(2, 3) }
        #undef APPL
    }
}

template<int Q1, int Q2>
__device__ __forceinline__ void convg(float2 a[4], const float* __restrict__ p, int lane) {
    rzg<Q2>(a, -0.5f * PI_F, lane);
    cxg<Q2, Q1>(a, lane);
    rzg<Q1>(a, p[0], lane);
    ryg<Q2>(a, p[1], lane);
    cxg<Q1, Q2>(a, lane);
    ryg<Q2>(a, p[2], lane);
    cxg<Q2, Q1>(a, lane);
    rzg<Q1>(a, 0.5f * PI_F, lane);
}

template<int Q1, int Q2>
__device__ __forceinline__ void poolg(float2 a[4], const float* __restrict__ p, int lane) {
    rzg<Q2>(a, -0.5f * PI_F, lane);
    cxg<Q2, Q1>(a, lane);
    rzg<Q1>(a, p[0], lane);
    ryg<Q2>(a, p[1], lane);
    cxg<Q1, Q2>(a, lane);
    ryg<Q2>(a, p[2], lane);
}

// ---------------------------------------------------------------------------
// QLSTM helpers (identical math to round 4)
// ---------------------------------------------------------------------------

template<int CTRL>
__device__ __forceinline__ float bq(float v) {
    return __int_as_float(__builtin_amdgcn_update_dpp(0, __float_as_int(v), CTRL, 0xF, 0xF, true));
}

__device__ __forceinline__ float pick4(bool b0, bool b1, float a0, float a1, float a2, float a3) {
    float t01 = b0 ? a1 : a0;
    float t23 = b0 ? a3 : a2;
    return b1 ? t23 : t01;
}

// ---------------------------------------------------------------------------
// Fused kernel: block 0 = qlstm consumer wave; blocks 1..512 = qcnn producers.
// Handshake: per-sample flag in d_ws (poison 0xAAAAAAAA != magic -> no init
// needed). Producer: relaxed-agent data store, release-agent flag store.
// Consumer: acquire-agent flag polls in chunks of 32 timesteps, then stages
// to LDS and runs the recurrence -> makespan ~ max(qcnn, qlstm).
// ---------------------------------------------------------------------------

__global__ __launch_bounds__(256) void fused_kernel(
    const float* __restrict__ x, const float* __restrict__ w,
    const float* __restrict__ thf, const float* __restrict__ thi,
    const float* __restrict__ thg, const float* __restrict__ tho,
    const float* __restrict__ Wf, const float* __restrict__ bf,
    const float* __restrict__ Wi, const float* __restrict__ bi,
    const float* __restrict__ Wg, const float* __restrict__ bg,
    const float* __restrict__ Wo, const float* __restrict__ bo,
    const float* __restrict__ Wh, const float* __restrict__ bh,
    float* out, unsigned int* flags) {

    if (blockIdx.x != 0) {
        // ---------------- QCNN producer ----------------
        int lane = threadIdx.x & 63;
        int n = (blockIdx.x - 1) * 4 + (threadIdx.x >> 6);
        float2 a[4];
        a[0] = make_float2(lane == 0 ? 1.0f : 0.0f, 0.0f);
        a[1] = make_float2(0.0f, 0.0f);
        a[2] = make_float2(0.0f, 0.0f);
        a[3] = make_float2(0.0f, 0.0f);

        const float* xr = x + n * 8;
        featg<0>(a, xr[0], lane);
        featg<1>(a, xr[1], lane);
        featg<2>(a, xr[2], lane);
        featg<3>(a, xr[3], lane);
        featg<4>(a, xr[4], lane);
        featg<5>(a, xr[5], lane);
        featg<6>(a, xr[6], lane);
        featg<7>(a, xr[7], lane);

        convg<0,1>(a, w + 0,  lane);
        convg<2,3>(a, w + 3,  lane);
        convg<4,5>(a, w + 6,  lane);
        convg<6,7>(a, w + 9,  lane);
        poolg<0,1>(a, w + 12, lane);
        poolg<2,3>(a, w + 15, lane);
        poolg<4,5>(a, w + 18, lane);
        poolg<6,7>(a, w + 21, lane);
        convg<0,1>(a, w + 24, lane);
        convg<2,3>(a, w + 27, lane);
        poolg<0,1>(a, w + 30, lane);
        poolg<2,3>(a, w + 33, lane);
        convg<0,1>(a, w + 36, lane);
        poolg<0,1>(a, w + 39, lane);

        float ssum = 0.f;
        #pragma unroll
        for (int r = 0; r < 4; ++r)
            ssum += a[r].x * a[r].x + a[r].y * a[r].y;
        ssum = (lane & 32) ? -ssum : ssum;
        #pragma unroll
        for (int m = 1; m < 64; m <<= 1)
            ssum += __shfl_xor(ssum, m, 64);
        if (lane == 0) {
            __hip_atomic_store((unsigned int*)(out + n), __float_as_uint(ssum),
                               __ATOMIC_RELAXED, __HIP_MEMORY_SCOPE_AGENT);
            __hip_atomic_store(flags + n, FLAG_MAGIC,
                               __ATOMIC_RELEASE, __HIP_MEMORY_SCOPE_AGENT);
        }
        return;
    }

    // ---------------- QLSTM consumer (block 0, wave 0 only) ----------------
    if (threadIdx.x >= 64) return;
    int lane = threadIdx.x;
    int b = lane >> 2, q = lane & 3;
    bool qb0 = q & 1, qb1 = q & 2;

    __shared__ __align__(16) float qsh[16 * 132];

    const float* Wp = (q == 0) ? Wf : (q == 1) ? Wi : (q == 2) ? Wg : Wo;
    const float* bp = (q == 0) ? bf : (q == 1) ? bi : (q == 2) ? bg : bo;
    const float* tp = (q == 0) ? thf : (q == 1) ? thi : (q == 2) ? thg : tho;

    float W[20], av[4];
    #pragma unroll
    for (int k = 0; k < 20; ++k) W[k] = Wp[k];
    #pragma unroll
    for (int r = 0; r < 4; ++r) av[r] = bp[r] + tp[r];

    float nA = (q == 2) ? 1.0f : 0.0f;
    float nB = (q == 2) ? -2.0f : 1.0f;
    float nK = (q == 2) ? 2.0f : -1.0f;

    float c = 0.f;
    float h0 = 0.f, h1 = 0.f, h2 = 0.f, h3 = 0.f;

    // staging assignment: this lane stages 8 samples of batch b: t = c*32 + (q*8..q*8+7)
    int j0 = q * 8;
    const unsigned int* qcu = (const unsigned int*)out;

    for (int ch = 0; ch < 4; ++ch) {
        int tbase = ch * 32 + j0;
        const unsigned int* fp = flags + b * 128 + tbase;
        // wait until all 8 flags set (pipelined loads; usually one pass)
        for (;;) {
            unsigned int d = 0;
            #pragma unroll
            for (int k = 0; k < 8; ++k)
                d |= __hip_atomic_load(fp + k, __ATOMIC_ACQUIRE, __HIP_MEMORY_SCOPE_AGENT) ^ FLAG_MAGIC;
            if (d == 0) break;
            __builtin_amdgcn_s_sleep(2);
        }
        // stage data to LDS
        #pragma unroll
        for (int k = 0; k < 8; ++k) {
            unsigned int u = __hip_atomic_load(qcu + b * 128 + tbase + k,
                                               __ATOMIC_RELAXED, __HIP_MEMORY_SCOPE_AGENT);
            qsh[b * 132 + tbase + k] = __uint_as_float(u);
        }
        __builtin_amdgcn_wave_barrier();   // single wave: LDS ops program-ordered

        float xv = qsh[b * 132 + ch * 32];
        for (int j = 0; j < 32; ++j) {
            int t = ch * 32 + j;
            float xn = qsh[b * 132 + t + 1];   // t=127 -> padding slot (unused next iter)
            float vA = av[0] + W[0]*xv  + W[1]*h0  + W[2]*h1  + W[3]*h2  + W[4]*h3;
            float vB = av[1] + W[5]*xv  + W[6]*h0  + W[7]*h1  + W[8]*h2  + W[9]*h3;
            float vC = av[2] + W[10]*xv + W[11]*h0 + W[12]*h1 + W[13]*h2 + W[14]*h3;
            float vD = av[3] + W[15]*xv + W[16]*h0 + W[17]*h1 + W[18]*h2 + W[19]*h3;
            float cA = __cosf(vA), cB = __cosf(vB), cC = __cosf(vC), cD = __cosf(vD);
            float r1 = cA * cB, r2 = r1 * cC, r3 = r2 * cD, r0 = cB * (cC * cD);
            float E0 = __expf(nK * r0), E1 = __expf(nK * r1);
            float E2 = __expf(nK * r2), E3 = __expf(nK * r3);
            float n0 = nA + nB * rcpf(E0 + 1.0f);
            float n1 = nA + nB * rcpf(E1 + 1.0f);
            float n2 = nA + nB * rcpf(E2 + 1.0f);
            float n3 = nA + nB * rcpf(E3 + 1.0f);
            float F0 = bq<0x00>(n0), F1 = bq<0x00>(n1), F2 = bq<0x00>(n2), F3 = bq<0x00>(n3);
            float I0 = bq<0x55>(n0), I1 = bq<0x55>(n1), I2 = bq<0x55>(n2), I3 = bq<0x55>(n3);
            float G0 = bq<0xAA>(n0), G1 = bq<0xAA>(n1), G2 = bq<0xAA>(n2), G3 = bq<0xAA>(n3);
            float O0 = bq<0xFF>(n0), O1 = bq<0xFF>(n1), O2 = bq<0xFF>(n2), O3 = bq<0xFF>(n3);
            float F = pick4(qb0, qb1, F0, F1, F2, F3);
            float I = pick4(qb0, qb1, I0, I1, I2, I3);
            float G = pick4(qb0, qb1, G0, G1, G2, G3);
            float O = pick4(qb0, qb1, O0, O1, O2, O3);
            c = F * c + I * G;
            float Ec = __expf(2.0f * c);
            float tau = 1.0f - 2.0f * rcpf(Ec + 1.0f);
            float hq = O * tau;
            h0 = bq<0x00>(hq);
            h1 = bq<0x55>(hq);
            h2 = bq<0xAA>(hq);
            h3 = bq<0xFF>(hq);
            xv = xn;
        }
    }

    if (q == 0)
        out[2048 + b] = bh[0] + Wh[0]*h0 + Wh[1]*h1 + Wh[2]*h2 + Wh[3]*h3;
}

extern "C" void kernel_launch(void* const* d_in, const int* in_sizes, int n_in,
                              void* d_out, int out_size, void* d_ws, size_t ws_size,
                              hipStream_t stream) {
    const float* x = (const float*)d_in[0];
    const float* w = (const float*)d_in[1];
    float* out = (float*)d_out;
    unsigned int* flags = (unsigned int*)d_ws;

    fused_kernel<<<513, 256, 0, stream>>>(
        x, w,
        (const float*)d_in[2], (const float*)d_in[3],
        (const float*)d_in[4], (const float*)d_in[5],
        (const float*)d_in[6], (const float*)d_in[7],
        (const float*)d_in[8], (const float*)d_in[9],
        (const float*)d_in[10], (const float*)d_in[11],
        (const float*)d_in[12], (const float*)d_in[13],
        (const float*)d_in[14], (const float*)d_in[15],
        out, flags);
}

// Round 6
// 126.932 us; speedup vs baseline: 1.1079x; 1.1079x over previous
//
#include <hip/hip_runtime.h>
#include <math.h>

#define PI_F 3.14159265358979323846f
#define FLAG_MAGIC 0x5EEDCAFEu

__device__ __forceinline__ float rcpf(float x) { return __builtin_amdgcn_rcpf(x); }
__device__ __forceinline__ void fswap(float2& p, float2& q) { float2 t = p; p = q; q = t; }

// ---------------------------------------------------------------------------
// QCNN per-wave register statevector (identical math to rounds 4/5).
// Amp mapping: qubit0 -> reg bit1, qubit1 -> reg bit0, qubit q>=2 -> lane bit (q-2).
// ---------------------------------------------------------------------------

template<int Q>
__device__ __forceinline__ float exq(float v) {
    if constexpr (Q == 2)
        return __int_as_float(__builtin_amdgcn_update_dpp(0, __float_as_int(v), 0xB1, 0xF, 0xF, true));
    else if constexpr (Q == 3)
        return __int_as_float(__builtin_amdgcn_update_dpp(0, __float_as_int(v), 0x4E, 0xF, 0xF, true));
    else if constexpr (Q == 4)
        return __int_as_float(__builtin_amdgcn_ds_swizzle(__float_as_int(v), 0x101F));
    else if constexpr (Q == 5)
        return __int_as_float(__builtin_amdgcn_ds_swizzle(__float_as_int(v), 0x201F));
    else if constexpr (Q == 6)
        return __int_as_float(__builtin_amdgcn_ds_swizzle(__float_as_int(v), 0x401F));
    else
        return __shfl_xor(v, 32, 64);
}

template<int Q>
__device__ __forceinline__ void rzg(float2 a[4], float th, int lane) {
    float c = __cosf(0.5f * th), s = __sinf(0.5f * th);
    if constexpr (Q >= 2) {
        float se = ((lane >> (Q - 2)) & 1) ? s : -s;
        #pragma unroll
        for (int r = 0; r < 4; ++r) {
            float nx = c * a[r].x - se * a[r].y;
            float ny = c * a[r].y + se * a[r].x;
            a[r] = make_float2(nx, ny);
        }
    } else {
        #pragma unroll
        for (int r = 0; r < 4; ++r) {
            int bit = (Q == 0) ? (r >> 1) : (r & 1);
            float se = bit ? s : -s;
            float nx = c * a[r].x - se * a[r].y;
            float ny = c * a[r].y + se * a[r].x;
            a[r] = make_float2(nx, ny);
        }
    }
}

template<int Q>
__device__ __forceinline__ void ryg(float2 a[4], float th, int lane) {
    float c = __cosf(0.5f * th), s = __sinf(0.5f * th);
    if constexpr (Q >= 2) {
        float se = ((lane >> (Q - 2)) & 1) ? s : -s;
        #pragma unroll
        for (int r = 0; r < 4; ++r) {
            float ox = exq<Q>(a[r].x), oy = exq<Q>(a[r].y);
            a[r] = make_float2(c * a[r].x + se * ox, c * a[r].y + se * oy);
        }
    } else if constexpr (Q == 0) {
        #pragma unroll
        for (int r = 0; r < 2; ++r) {
            float2 lo = a[r], hi = a[r + 2];
            a[r]     = make_float2(c * lo.x - s * hi.x, c * lo.y - s * hi.y);
            a[r + 2] = make_float2(s * lo.x + c * hi.x, s * lo.y + c * hi.y);
        }
    } else {
        #pragma unroll
        for (int r = 0; r < 4; r += 2) {
            float2 lo = a[r], hi = a[r + 1];
            a[r]     = make_float2(c * lo.x - s * hi.x, c * lo.y - s * hi.y);
            a[r + 1] = make_float2(s * lo.x + c * hi.x, s * lo.y + c * hi.y);
        }
    }
}

template<int C, int T>
__device__ __forceinline__ void cxg(float2 a[4], int lane) {
    if constexpr (C >= 2) {
        bool cb = (lane >> (C - 2)) & 1;
        #pragma unroll
        for (int r = 0; r < 4; ++r) {
            float ox = exq<T>(a[r].x), oy = exq<T>(a[r].y);
            a[r].x = cb ? ox : a[r].x;
            a[r].y = cb ? oy : a[r].y;
        }
    } else if constexpr (C == 0 && T == 1) {
        fswap(a[2], a[3]);
    } else {
        fswap(a[1], a[3]);
    }
}

template<int Q>
__device__ __forceinline__ void featg(float2 a[4], float xq, int lane) {
    float phi = 2.0f * xq;
    float e1x = __cosf(phi), e1y = __sinf(phi);
    float e2x = e1x * e1x - e1y * e1y;
    float e2y = 2.0f * e1x * e1y;
    float2 u00 = make_float2(0.5f * (1.0f + e1x),  0.5f * e1y);
    float2 u01 = make_float2(0.5f * (1.0f - e1x), -0.5f * e1y);
    float2 u10 = make_float2(0.5f * (e1x - e2x), 0.5f * (e1y - e2y));
    float2 u11 = make_float2(0.5f * (e1x + e2x), 0.5f * (e1y + e2y));
    if constexpr (Q >= 2) {
        bool bset = (lane >> (Q - 2)) & 1;
        float csx = bset ? u11.x : u00.x, csy = bset ? u11.y : u00.y;
        float cox = bset ? u10.x : u01.x, coy = bset ? u10.y : u01.y;
        #pragma unroll
        for (int r = 0; r < 4; ++r) {
            float ox = exq<Q>(a[r].x), oy = exq<Q>(a[r].y);
            float nx = csx * a[r].x - csy * a[r].y + cox * ox - coy * oy;
            float ny = csx * a[r].y + csy * a[r].x + cox * oy + coy * ox;
            a[r] = make_float2(nx, ny);
        }
    } else {
        float2 l, h;
        #define APPL(LO, HI)                                                        \
            l = a[LO]; h = a[HI];                                                   \
            a[LO] = make_float2(u00.x*l.x - u00.y*l.y + u01.x*h.x - u01.y*h.y,      \
                                u00.x*l.y + u00.y*l.x + u01.x*h.y + u01.y*h.x);     \
            a[HI] = make_float2(u10.x*l.x - u10.y*l.y + u11.x*h.x - u11.y*h.y,      \
                                u10.x*l.y + u10.y*l.x + u11.x*h.y + u11.y*h.x);
        if constexpr (Q == 0) { APPL(0, 2) APPL(1, 3) }
        else                  { APPL(0, 1) APPL(2, 3) }
        #undef APPL
    }
}

template<int Q1, int Q2>
__device__ __forceinline__ void convg(float2 a[4], const float* __restrict__ p, int lane) {
    rzg<Q2>(a, -0.5f * PI_F, lane);
    cxg<Q2, Q1>(a, lane);
    rzg<Q1>(a, p[0], lane);
    ryg<Q2>(a, p[1], lane);
    cxg<Q1, Q2>(a, lane);
    ryg<Q2>(a, p[2], lane);
    cxg<Q2, Q1>(a, lane);
    rzg<Q1>(a, 0.5f * PI_F, lane);
}

template<int Q1, int Q2>
__device__ __forceinline__ void poolg(float2 a[4], const float* __restrict__ p, int lane) {
    rzg<Q2>(a, -0.5f * PI_F, lane);
    cxg<Q2, Q1>(a, lane);
    rzg<Q1>(a, p[0], lane);
    ryg<Q2>(a, p[1], lane);
    cxg<Q1, Q2>(a, lane);
    ryg<Q2>(a, p[2], lane);
}

// ---------------------------------------------------------------------------
// QLSTM helpers
// ---------------------------------------------------------------------------

template<int CTRL>
__device__ __forceinline__ float bq(float v) {   // quad_perm broadcast/permute
    return __int_as_float(__builtin_amdgcn_update_dpp(0, __float_as_int(v), CTRL, 0xF, 0xF, true));
}

template<int PAT>
__device__ __forceinline__ float swz(float v) {  // ds_swizzle, imm pattern
    return __int_as_float(__builtin_amdgcn_ds_swizzle(__float_as_int(v), PAT));
}

__device__ __forceinline__ float pick4(bool b0, bool b1, float a0, float a1, float a2, float a3) {
    float t01 = b0 ? a1 : a0;
    float t23 = b0 ? a3 : a2;
    return b1 ? t23 : t01;
}

// ---------------------------------------------------------------------------
// Fused kernel: block 0 = qlstm consumer (ALL 256 threads: lane=(b,q,r), one
// row-element per lane -> 5 W regs/lane, ~40 instr/step);
// blocks 1..512 = qcnn producers. Handshake via per-sample flags in d_ws.
// ---------------------------------------------------------------------------

__global__ __launch_bounds__(256) void fused_kernel(
    const float* __restrict__ x, const float* __restrict__ w,
    const float* __restrict__ thf, const float* __restrict__ thi,
    const float* __restrict__ thg, const float* __restrict__ tho,
    const float* __restrict__ Wf, const float* __restrict__ bf,
    const float* __restrict__ Wi, const float* __restrict__ bi,
    const float* __restrict__ Wg, const float* __restrict__ bg,
    const float* __restrict__ Wo, const float* __restrict__ bo,
    const float* __restrict__ Wh, const float* __restrict__ bh,
    float* out, unsigned int* flags) {

    if (blockIdx.x != 0) {
        // ---------------- QCNN producer ----------------
        int lane = threadIdx.x & 63;
        int n = (blockIdx.x - 1) * 4 + (threadIdx.x >> 6);
        float2 a[4];
        a[0] = make_float2(lane == 0 ? 1.0f : 0.0f, 0.0f);
        a[1] = make_float2(0.0f, 0.0f);
        a[2] = make_float2(0.0f, 0.0f);
        a[3] = make_float2(0.0f, 0.0f);

        const float* xr = x + n * 8;
        featg<0>(a, xr[0], lane);
        featg<1>(a, xr[1], lane);
        featg<2>(a, xr[2], lane);
        featg<3>(a, xr[3], lane);
        featg<4>(a, xr[4], lane);
        featg<5>(a, xr[5], lane);
        featg<6>(a, xr[6], lane);
        featg<7>(a, xr[7], lane);

        convg<0,1>(a, w + 0,  lane);
        convg<2,3>(a, w + 3,  lane);
        convg<4,5>(a, w + 6,  lane);
        convg<6,7>(a, w + 9,  lane);
        poolg<0,1>(a, w + 12, lane);
        poolg<2,3>(a, w + 15, lane);
        poolg<4,5>(a, w + 18, lane);
        poolg<6,7>(a, w + 21, lane);
        convg<0,1>(a, w + 24, lane);
        convg<2,3>(a, w + 27, lane);
        poolg<0,1>(a, w + 30, lane);
        poolg<2,3>(a, w + 33, lane);
        convg<0,1>(a, w + 36, lane);
        poolg<0,1>(a, w + 39, lane);

        float ssum = 0.f;
        #pragma unroll
        for (int r = 0; r < 4; ++r)
            ssum += a[r].x * a[r].x + a[r].y * a[r].y;
        ssum = (lane & 32) ? -ssum : ssum;
        #pragma unroll
        for (int m = 1; m < 64; m <<= 1)
            ssum += __shfl_xor(ssum, m, 64);
        if (lane == 0) {
            __hip_atomic_store((unsigned int*)(out + n), __float_as_uint(ssum),
                               __ATOMIC_RELAXED, __HIP_MEMORY_SCOPE_AGENT);
            __hip_atomic_store(flags + n, FLAG_MAGIC,
                               __ATOMIC_RELEASE, __HIP_MEMORY_SCOPE_AGENT);
        }
        return;
    }

    // ---------------- QLSTM consumer: lane = (b, gate q, row r) ----------------
    // lane bits: [5:4]=b_local within wave, [3:2]=q, [1:0]=r; b = wave*4+b_local.
    // Closed-form qgate: c_i = cos(v_i + th_i); rows = [c1c2c3, c0c1, c0c1c2, c0c1c2c3].
    int tid = threadIdx.x;
    int ln = tid & 63;
    int b  = (tid >> 6) * 4 + (ln >> 4);
    int qr = ln & 15;
    int q  = qr >> 2, r = qr & 3;
    bool qb0 = q & 1, qb1 = q & 2;
    bool rb0 = r & 1, rb1 = r & 2;

    __shared__ __align__(16) float qsh[16 * 132];   // padded rows

    const float* Wp = (q == 0) ? Wf : (q == 1) ? Wi : (q == 2) ? Wg : Wo;
    const float* bp = (q == 0) ? bf : (q == 1) ? bi : (q == 2) ? bg : bo;
    const float* tp = (q == 0) ? thf : (q == 1) ? thi : (q == 2) ? thg : tho;

    float W0 = Wp[r * 5 + 0], W1 = Wp[r * 5 + 1], W2 = Wp[r * 5 + 2];
    float W3 = Wp[r * 5 + 3], W4 = Wp[r * 5 + 4];
    float av = bp[r] + tp[r];

    // nonlinearity for gate q:  n = A + B * rcp(exp(K*x) + 1)
    float nAq = (q == 2) ? 1.0f : 0.0f;
    float nBq = (q == 2) ? -2.0f : 1.0f;
    float nKq = (q == 2) ? 2.0f : -1.0f;

    float c = 0.f;                                   // state row r (redundant over q)
    float h0 = 0.f, h1 = 0.f, h2 = 0.f, h3 = 0.f;    // broadcast h

    const unsigned int* qcu = (const unsigned int*)out;
    int tA = qr << 1;                                // this lane stages t = ch*32 + tA, +1

    for (int ch = 0; ch < 4; ++ch) {
        int tbase = ch * 32 + tA;
        const unsigned int* fp = flags + b * 128 + tbase;
        for (;;) {
            unsigned int u0 = __hip_atomic_load(fp,     __ATOMIC_ACQUIRE, __HIP_MEMORY_SCOPE_AGENT);
            unsigned int u1 = __hip_atomic_load(fp + 1, __ATOMIC_ACQUIRE, __HIP_MEMORY_SCOPE_AGENT);
            if (((u0 ^ FLAG_MAGIC) | (u1 ^ FLAG_MAGIC)) == 0) break;
            __builtin_amdgcn_s_sleep(2);
        }
        unsigned int d0 = __hip_atomic_load(qcu + b * 128 + tbase,
                                            __ATOMIC_RELAXED, __HIP_MEMORY_SCOPE_AGENT);
        unsigned int d1 = __hip_atomic_load(qcu + b * 128 + tbase + 1,
                                            __ATOMIC_RELAXED, __HIP_MEMORY_SCOPE_AGENT);
        qsh[b * 132 + tbase]     = __uint_as_float(d0);
        qsh[b * 132 + tbase + 1] = __uint_as_float(d1);
        __builtin_amdgcn_wave_barrier();   // per-wave staging region; wave-ordered LDS

        float xv = qsh[b * 132 + ch * 32];
        for (int j = 0; j < 32; ++j) {
            int t = ch * 32 + j;
            float xn = qsh[b * 132 + t + 1];   // last j reads pad/next slot; re-init next chunk
            // own row's pre-activation and cosine
            float v = av + W0 * xv + W1 * h0 + W2 * h1 + W3 * h2 + W4 * h3;
            float cr = __cosf(v);
            // gather this gate's 4 row-cosines (r = quad position)
            float c0 = bq<0x00>(cr), c1 = bq<0x55>(cr), c2 = bq<0xAA>(cr), c3 = bq<0xFF>(cr);
            float p01 = c0 * c1, p012 = p01 * c2, p0123 = p012 * c3, p123 = c1 * (c2 * c3);
            float rr = pick4(rb0, rb1, p123, p01, p012, p0123);
            // nonlinearity for this gate
            float E = __expf(nKq * rr);
            float n = nAq + nBq * rcpf(E + 1.0f);
            // cross-gate exchange: xor lane bits 2-3
            float s1 = swz<0x101F>(n);   // gate q^1
            float s2 = swz<0x201F>(n);   // gate q^2
            float s3 = swz<0x301F>(n);   // gate q^3
            float F = pick4(qb0, qb1, n,  s1, s2, s3);
            float I = pick4(qb0, qb1, s1, n,  s3, s2);
            float G = pick4(qb0, qb1, s2, s3, n,  s1);
            float O = pick4(qb0, qb1, s3, s2, s1, n);
            c = F * c + I * G;
            float Ec = __expf(2.0f * c);
            float tau = 1.0f - 2.0f * rcpf(Ec + 1.0f);
            float hr = O * tau;
            h0 = bq<0x00>(hr);
            h1 = bq<0x55>(hr);
            h2 = bq<0xAA>(hr);
            h3 = bq<0xFF>(hr);
            xv = xn;
        }
    }

    if (qr == 0)
        out[2048 + b] = bh[0] + Wh[0]*h0 + Wh[1]*h1 + Wh[2]*h2 + Wh[3]*h3;
}

extern "C" void kernel_launch(void* const* d_in, const int* in_sizes, int n_in,
                              void* d_out, int out_size, void* d_ws, size_t ws_size,
                              hipStream_t stream) {
    const float* x = (const float*)d_in[0];
    const float* w = (const float*)d_in[1];
    float* out = (float*)d_out;
    unsigned int* flags = (unsigned int*)d_ws;

    fused_kernel<<<513, 256, 0, stream>>>(
        x, w,
        (const float*)d_in[2], (const float*)d_in[3],
        (const float*)d_in[4], (const float*)d_in[5],
        (const float*)d_in[6], (const float*)d_in[7],
        (const float*)d_in[8], (const float*)d_in[9],
        (const float*)d_in[10], (const float*)d_in[11],
        (const float*)d_in[12], (const float*)d_in[13],
        (const float*)d_in[14], (const float*)d_in[15],
        out, flags);
}

// Round 8
// 126.043 us; speedup vs baseline: 1.1157x; 1.0071x over previous
//
#include <hip/hip_runtime.h>
#include <math.h>

#define PI_F  3.14159265358979323846f
#define RSQ2F 0.70710678118654752f

__device__ __forceinline__ float rcpf(float x) { return __builtin_amdgcn_rcpf(x); }
__device__ __forceinline__ void fswap(float2& p, float2& q) { float2 t = p; p = q; q = t; }

// ---------------------------------------------------------------------------
// QCNN: one wave per sample (4 waves / 256-thread block), 256-amp state in
// registers (4 float2/lane). qubit0 -> reg bit1, qubit1 -> reg bit0,
// qubit q>=2 -> lane bit (q-2). Exchanges: q2,q3 DPP quad_perm; q4,q5,q6
// ds_swizzle; q7 shfl_xor(32). Diagonal gates need no exchange.
// RZ(±pi/2) constant-folded (verified round 7: output 0 passed).
// ---------------------------------------------------------------------------

template<int Q>
__device__ __forceinline__ float exq(float v) {
    if constexpr (Q == 2)
        return __int_as_float(__builtin_amdgcn_update_dpp(0, __float_as_int(v), 0xB1, 0xF, 0xF, true));
    else if constexpr (Q == 3)
        return __int_as_float(__builtin_amdgcn_update_dpp(0, __float_as_int(v), 0x4E, 0xF, 0xF, true));
    else if constexpr (Q == 4)
        return __int_as_float(__builtin_amdgcn_ds_swizzle(__float_as_int(v), 0x101F));
    else if constexpr (Q == 5)
        return __int_as_float(__builtin_amdgcn_ds_swizzle(__float_as_int(v), 0x201F));
    else if constexpr (Q == 6)
        return __int_as_float(__builtin_amdgcn_ds_swizzle(__float_as_int(v), 0x401F));
    else
        return __shfl_xor(v, 32, 64);
}

// RZ with precomputed c = cos(th/2), s = sin(th/2): diag(e^{-i th/2}, e^{+i th/2})
template<int Q>
__device__ __forceinline__ void rzg_cs(float2 a[4], float c, float s, int lane) {
    if constexpr (Q >= 2) {
        float se = ((lane >> (Q - 2)) & 1) ? s : -s;
        #pragma unroll
        for (int r = 0; r < 4; ++r) {
            float nx = c * a[r].x - se * a[r].y;
            float ny = c * a[r].y + se * a[r].x;
            a[r] = make_float2(nx, ny);
        }
    } else {
        #pragma unroll
        for (int r = 0; r < 4; ++r) {
            int bit = (Q == 0) ? (r >> 1) : (r & 1);
            float se = bit ? s : -s;
            float nx = c * a[r].x - se * a[r].y;
            float ny = c * a[r].y + se * a[r].x;
            a[r] = make_float2(nx, ny);
        }
    }
}

template<int Q>
__device__ __forceinline__ void rzg(float2 a[4], float th, int lane) {
    rzg_cs<Q>(a, __cosf(0.5f * th), __sinf(0.5f * th), lane);
}

template<int Q>
__device__ __forceinline__ void ryg(float2 a[4], float th, int lane) {
    float c = __cosf(0.5f * th), s = __sinf(0.5f * th);
    if constexpr (Q >= 2) {
        float se = ((lane >> (Q - 2)) & 1) ? s : -s;
        #pragma unroll
        for (int r = 0; r < 4; ++r) {
            float ox = exq<Q>(a[r].x), oy = exq<Q>(a[r].y);
            a[r] = make_float2(c * a[r].x + se * ox, c * a[r].y + se * oy);
        }
    } else if constexpr (Q == 0) {
        #pragma unroll
        for (int r = 0; r < 2; ++r) {
            float2 lo = a[r], hi = a[r + 2];
            a[r]     = make_float2(c * lo.x - s * hi.x, c * lo.y - s * hi.y);
            a[r + 2] = make_float2(s * lo.x + c * hi.x, s * lo.y + c * hi.y);
        }
    } else {
        #pragma unroll
        for (int r = 0; r < 4; r += 2) {
            float2 lo = a[r], hi = a[r + 1];
            a[r]     = make_float2(c * lo.x - s * hi.x, c * lo.y - s * hi.y);
            a[r + 1] = make_float2(s * lo.x + c * hi.x, s * lo.y + c * hi.y);
        }
    }
}

template<int C, int T>
__device__ __forceinline__ void cxg(float2 a[4], int lane) {
    if constexpr (C >= 2) {
        bool cb = (lane >> (C - 2)) & 1;
        #pragma unroll
        for (int r = 0; r < 4; ++r) {
            float ox = exq<T>(a[r].x), oy = exq<T>(a[r].y);
            a[r].x = cb ? ox : a[r].x;
            a[r].y = cb ? oy : a[r].y;
        }
    } else if constexpr (C == 0 && T == 1) {
        fswap(a[2], a[3]);
    } else {
        fswap(a[1], a[3]);
    }
}

template<int Q>
__device__ __forceinline__ void featg(float2 a[4], float xq, int lane) {
    float phi = 2.0f * xq;
    float e1x = __cosf(phi), e1y = __sinf(phi);
    float e2x = e1x * e1x - e1y * e1y;
    float e2y = 2.0f * e1x * e1y;
    float2 u00 = make_float2(0.5f * (1.0f + e1x),  0.5f * e1y);
    float2 u01 = make_float2(0.5f * (1.0f - e1x), -0.5f * e1y);
    float2 u10 = make_float2(0.5f * (e1x - e2x), 0.5f * (e1y - e2y));
    float2 u11 = make_float2(0.5f * (e1x + e2x), 0.5f * (e1y + e2y));
    if constexpr (Q >= 2) {
        bool bset = (lane >> (Q - 2)) & 1;
        float csx = bset ? u11.x : u00.x, csy = bset ? u11.y : u00.y;
        float cox = bset ? u10.x : u01.x, coy = bset ? u10.y : u01.y;
        #pragma unroll
        for (int r = 0; r < 4; ++r) {
            float ox = exq<Q>(a[r].x), oy = exq<Q>(a[r].y);
            float nx = csx * a[r].x - csy * a[r].y + cox * ox - coy * oy;
            float ny = csx * a[r].y + csy * a[r].x + cox * oy + coy * ox;
            a[r] = make_float2(nx, ny);
        }
    } else {
        float2 l, h;
        #define APPL(LO, HI)                                                        \
            l = a[LO]; h = a[HI];                                                   \
            a[LO] = make_float2(u00.x*l.x - u00.y*l.y + u01.x*h.x - u01.y*h.y,      \
                                u00.x*l.y + u00.y*l.x + u01.x*h.y + u01.y*h.x);     \
            a[HI] = make_float2(u10.x*l.x - u10.y*l.y + u11.x*h.x - u11.y*h.y,      \
                                u10.x*l.y + u10.y*l.x + u11.x*h.y + u11.y*h.x);
        if constexpr (Q == 0) { APPL(0, 2) APPL(1, 3) }
        else                  { APPL(0, 1) APPL(2, 3) }
        #undef APPL
    }
}

template<int Q1, int Q2>
__device__ __forceinline__ void convg(float2 a[4], const float* __restrict__ p, int lane) {
    rzg_cs<Q2>(a, RSQ2F, -RSQ2F, lane);   // RZ(-pi/2)
    cxg<Q2, Q1>(a, lane);
    rzg<Q1>(a, p[0], lane);
    ryg<Q2>(a, p[1], lane);
    cxg<Q1, Q2>(a, lane);
    ryg<Q2>(a, p[2], lane);
    cxg<Q2, Q1>(a, lane);
    rzg_cs<Q1>(a, RSQ2F, RSQ2F, lane);    // RZ(+pi/2)
}

template<int Q1, int Q2>
__device__ __forceinline__ void poolg(float2 a[4], const float* __restrict__ p, int lane) {
    rzg_cs<Q2>(a, RSQ2F, -RSQ2F, lane);   // RZ(-pi/2)
    cxg<Q2, Q1>(a, lane);
    rzg<Q1>(a, p[0], lane);
    ryg<Q2>(a, p[1], lane);
    cxg<Q1, Q2>(a, lane);
    ryg<Q2>(a, p[2], lane);
}

__global__ __launch_bounds__(256) void qcnn_kernel(const float* __restrict__ x,
                                                   const float* __restrict__ w,
                                                   float* __restrict__ out) {
    int lane = threadIdx.x & 63;
    int n = blockIdx.x * 4 + (threadIdx.x >> 6);
    float2 a[4];
    a[0] = make_float2(lane == 0 ? 1.0f : 0.0f, 0.0f);
    a[1] = make_float2(0.0f, 0.0f);
    a[2] = make_float2(0.0f, 0.0f);
    a[3] = make_float2(0.0f, 0.0f);

    const float* xr = x + n * 8;
    featg<0>(a, xr[0], lane);
    featg<1>(a, xr[1], lane);
    featg<2>(a, xr[2], lane);
    featg<3>(a, xr[3], lane);
    featg<4>(a, xr[4], lane);
    featg<5>(a, xr[5], lane);
    featg<6>(a, xr[6], lane);
    featg<7>(a, xr[7], lane);

    convg<0,1>(a, w + 0,  lane);
    convg<2,3>(a, w + 3,  lane);
    convg<4,5>(a, w + 6,  lane);
    convg<6,7>(a, w + 9,  lane);
    poolg<0,1>(a, w + 12, lane);
    poolg<2,3>(a, w + 15, lane);
    poolg<4,5>(a, w + 18, lane);
    poolg<6,7>(a, w + 21, lane);
    convg<0,1>(a, w + 24, lane);
    convg<2,3>(a, w + 27, lane);
    poolg<0,1>(a, w + 30, lane);
    poolg<2,3>(a, w + 33, lane);
    convg<0,1>(a, w + 36, lane);
    poolg<0,1>(a, w + 39, lane);

    // <Z_q7>: q7 = lane bit5
    float ssum = 0.f;
    #pragma unroll
    for (int r = 0; r < 4; ++r)
        ssum += a[r].x * a[r].x + a[r].y * a[r].y;
    ssum = (lane & 32) ? -ssum : ssum;
    #pragma unroll
    for (int m = 1; m < 64; m <<= 1)
        ssum += __shfl_xor(ssum, m, 64);
    if (lane == 0) out[n] = ssum;
}

// ---------------------------------------------------------------------------
// QLSTM — exact round-4 verified body (absmax 0.0039).
// Closed-form qgate: c_i = cos(v_i + th_i);
//   rows = [c1c2c3, c0c1, c0c1c2, c0c1c2c3]
// lane = b*4 + q. Lane computes gate q's 4 rows; routing via 16 DPP quad
// broadcasts + pick4; lane owns state row q; h re-broadcast via 4 DPP.
// ---------------------------------------------------------------------------

template<int CTRL>
__device__ __forceinline__ float bq(float v) {   // quad_perm broadcast
    return __int_as_float(__builtin_amdgcn_update_dpp(0, __float_as_int(v), CTRL, 0xF, 0xF, true));
}

__device__ __forceinline__ float pick4(bool b0, bool b1, float a0, float a1, float a2, float a3) {
    float t01 = b0 ? a1 : a0;
    float t23 = b0 ? a3 : a2;
    return b1 ? t23 : t01;
}

__global__ __launch_bounds__(64) void qlstm_kernel(
    const float* __restrict__ qc,
    const float* __restrict__ thf, const float* __restrict__ thi,
    const float* __restrict__ thg, const float* __restrict__ tho,
    const float* __restrict__ Wf, const float* __restrict__ bf,
    const float* __restrict__ Wi, const float* __restrict__ bi,
    const float* __restrict__ Wg, const float* __restrict__ bg,
    const float* __restrict__ Wo, const float* __restrict__ bo,
    const float* __restrict__ Wh, const float* __restrict__ bh,
    float* __restrict__ out) {
    __shared__ __align__(16) float qsh[16 * 132];   // padded rows: conflict-free
    int lane = threadIdx.x;

    const float4* qc4 = (const float4*)qc;
    #pragma unroll
    for (int k = 0; k < 8; ++k) {
        int i = k * 64 + lane;
        float4 v = qc4[i];
        int b = i >> 5;
        int t = (i & 31) << 2;
        *(float4*)&qsh[b * 132 + t] = v;
    }
    __builtin_amdgcn_wave_barrier();     // single wave: LDS ops program-ordered

    int b = lane >> 2, q = lane & 3;
    bool qb0 = q & 1, qb1 = q & 2;
    const float* Wp = (q == 0) ? Wf : (q == 1) ? Wi : (q == 2) ? Wg : Wo;
    const float* bp = (q == 0) ? bf : (q == 1) ? bi : (q == 2) ? bg : bo;
    const float* tp = (q == 0) ? thf : (q == 1) ? thi : (q == 2) ? thg : tho;

    float W[20], av[4];
    #pragma unroll
    for (int k = 0; k < 20; ++k) W[k] = Wp[k];
    #pragma unroll
    for (int r = 0; r < 4; ++r) av[r] = bp[r] + tp[r];

    // gate-q nonlinearity: n = A + B*rcp(exp(K*x)+1)
    // sigma: A=0, B=1, K=-1;  tanh (q==2): A=1, B=-2, K=2
    float nA = (q == 2) ? 1.0f : 0.0f;
    float nB = (q == 2) ? -2.0f : 1.0f;
    float nK = (q == 2) ? 2.0f : -1.0f;

    float c = 0.f;                                   // state row q
    float h0 = 0.f, h1 = 0.f, h2 = 0.f, h3 = 0.f;    // broadcast h
    const float* qrow = &qsh[b * 132];
    float xv = qrow[0];

    for (int t = 0; t < 128; ++t) {
        float xn = qrow[t + 1];          // t=127 reads pad slot (unused)
        float vA = av[0] + W[0]*xv  + W[1]*h0  + W[2]*h1  + W[3]*h2  + W[4]*h3;
        float vB = av[1] + W[5]*xv  + W[6]*h0  + W[7]*h1  + W[8]*h2  + W[9]*h3;
        float vC = av[2] + W[10]*xv + W[11]*h0 + W[12]*h1 + W[13]*h2 + W[14]*h3;
        float vD = av[3] + W[15]*xv + W[16]*h0 + W[17]*h1 + W[18]*h2 + W[19]*h3;
        float cA = __cosf(vA), cB = __cosf(vB), cC = __cosf(vC), cD = __cosf(vD);
        float r1 = cA * cB, r2 = r1 * cC, r3 = r2 * cD, r0 = cB * (cC * cD);
        float E0 = __expf(nK * r0), E1 = __expf(nK * r1);
        float E2 = __expf(nK * r2), E3 = __expf(nK * r3);
        float n0 = nA + nB * rcpf(E0 + 1.0f);
        float n1 = nA + nB * rcpf(E1 + 1.0f);
        float n2 = nA + nB * rcpf(E2 + 1.0f);
        float n3 = nA + nB * rcpf(E3 + 1.0f);
        // broadcast all 16 gate x row values across the quad
        float F0 = bq<0x00>(n0), F1 = bq<0x00>(n1), F2 = bq<0x00>(n2), F3 = bq<0x00>(n3);
        float I0 = bq<0x55>(n0), I1 = bq<0x55>(n1), I2 = bq<0x55>(n2), I3 = bq<0x55>(n3);
        float G0 = bq<0xAA>(n0), G1 = bq<0xAA>(n1), G2 = bq<0xAA>(n2), G3 = bq<0xAA>(n3);
        float O0 = bq<0xFF>(n0), O1 = bq<0xFF>(n1), O2 = bq<0xFF>(n2), O3 = bq<0xFF>(n3);
        // pick own row q
        float F = pick4(qb0, qb1, F0, F1, F2, F3);
        float I = pick4(qb0, qb1, I0, I1, I2, I3);
        float G = pick4(qb0, qb1, G0, G1, G2, G3);
        float O = pick4(qb0, qb1, O0, O1, O2, O3);
        c = F * c + I * G;
        float Ec = __expf(2.0f * c);
        float tau = 1.0f - 2.0f * rcpf(Ec + 1.0f);
        float hq = O * tau;
        h0 = bq<0x00>(hq);
        h1 = bq<0x55>(hq);
        h2 = bq<0xAA>(hq);
        h3 = bq<0xFF>(hq);
        xv = xn;
    }

    if (q == 0)
        out[2048 + b] = bh[0] + Wh[0]*h0 + Wh[1]*h1 + Wh[2]*h2 + Wh[3]*h3;
}

extern "C" void kernel_launch(void* const* d_in, const int* in_sizes, int n_in,
                              void* d_out, int out_size, void* d_ws, size_t ws_size,
                              hipStream_t stream) {
    const float* x = (const float*)d_in[0];
    const float* w = (const float*)d_in[1];
    float* out = (float*)d_out;

    qcnn_kernel<<<512, 256, 0, stream>>>(x, w, out);
    qlstm_kernel<<<1, 64, 0, stream>>>(
        out,
        (const float*)d_in[2], (const float*)d_in[3],
        (const float*)d_in[4], (const float*)d_in[5],
        (const float*)d_in[6], (const float*)d_in[7],
        (const float*)d_in[8], (const float*)d_in[9],
        (const float*)d_in[10], (const float*)d_in[11],
        (const float*)d_in[12], (const float*)d_in[13],
        (const float*)d_in[14], (const float*)d_in[15],
        out);
}